// Round 9
// baseline (622.949 us; speedup 1.0000x reference)
//
#include <hip/hip_runtime.h>

// IcoPool: out[b,f,v] = mean_{k<7} x[b,f,idx[v,k]]
// x: (8, 64, 163842) f32, idx: (40962, 7) int32, out: (8, 64, 40962) f32
//
// v2-v8 history: interleaved fp16 slab (64B entry = 32 rows of one vertex),
//   quad-cooperative full-line gathers; fp16 halves fills; v8 made the slab
//   L3-resident (nt x-reads, regular slab stores) -17us.
// v9: pass 2 runs at 0.047 fills/cyc/CU = ~16 outstanding lines/CU at ~350cy
//   L3 latency -> per-CU TCP(L1) miss-buffer cap (explains v7's depth-null).
//   Fix: nontemporal gather LOADS (nt flag = L1 no-allocate) -> requests skip
//   the TCP miss FIFO and queue in the deeper TCC path. No L2 reuse exists to
//   lose (21MB/XCD random window); L3 is memory-side so slab lines (allocated
//   by pass-1 regular stores) still hit.

typedef float    f4 __attribute__((ext_vector_type(4)));
typedef float    f8 __attribute__((ext_vector_type(8)));
typedef _Float16 h8 __attribute__((ext_vector_type(8)));
typedef unsigned int u4 __attribute__((ext_vector_type(4)));

constexpr int B = 8, F = 64, V_IN = 163842, V_OUT = 40962, K = 7;
constexpr int ROWS = B * F;                        // 512
constexpr int RG   = 32;                           // rows per entry (64 B fp16)
constexpr int NG   = ROWS / RG;                    // 16 groups
constexpr int TPB  = 256;
constexpr int GPX  = NG / 8;                       // 2 groups per XCD
// pass 1
constexpr int CPB  = 256;                          // columns per block
constexpr int IBX  = (V_IN + CPB - 1) / CPB;       // 641
constexpr int LSH  = 34;                           // LDS halves per column (32+pad)
// pass 2
constexpr int VPB  = 64;                           // v per block (4 lanes each)
constexpr int VB   = (V_OUT + VPB - 1) / VPB;      // 641
constexpr int BLOCKS2 = 8 * VB;                    // 5128 (both groups per block)
constexpr size_t XH_BYTES = (size_t)NG * V_IN * 64; // 167.8 MB

static __device__ __forceinline__ h8 ntload_h8(const h8* p) {
    u4 r = __builtin_nontemporal_load((const u4*)p);
    union { u4 u; h8 h; } c; c.u = r; return c.h;
}

// ---- pass 1: transpose-pack 32 f32 rows -> 64B fp16 entries, via LDS ----
__global__ __launch_bounds__(TPB) void icopool_pack_h(
    const float* __restrict__ x, u4* __restrict__ xH)
{
    __shared__ _Float16 tile[CPB * LSH];           // 17408 B
    const int g  = blockIdx.y;
    const int c0 = blockIdx.x * CPB;
    const int t  = threadIdx.x;
    const int r  = t >> 3;                         // 0..31
    const int ci = t & 7;

    const float* xr = x + (size_t)(g * RG + r) * V_IN;
    if (c0 + CPB <= V_IN) {
        #pragma unroll
        for (int it = 0; it < 4; ++it) {
            const int c8 = ci * 8 + it * 64;
            const f4 v0 = __builtin_nontemporal_load((const f4*)(xr + c0 + c8));
            const f4 v1 = __builtin_nontemporal_load((const f4*)(xr + c0 + c8 + 4));
            tile[(c8 + 0) * LSH + r] = (_Float16)v0.x;
            tile[(c8 + 1) * LSH + r] = (_Float16)v0.y;
            tile[(c8 + 2) * LSH + r] = (_Float16)v0.z;
            tile[(c8 + 3) * LSH + r] = (_Float16)v0.w;
            tile[(c8 + 4) * LSH + r] = (_Float16)v1.x;
            tile[(c8 + 5) * LSH + r] = (_Float16)v1.y;
            tile[(c8 + 6) * LSH + r] = (_Float16)v1.z;
            tile[(c8 + 7) * LSH + r] = (_Float16)v1.w;
        }
    } else {
        for (int it = 0; it < 4; ++it) {
            const int c8 = ci * 8 + it * 64;
            for (int jj = 0; jj < 8; ++jj) {
                const int c = c0 + c8 + jj;
                tile[(c8 + jj) * LSH + r] =
                    (c < V_IN) ? (_Float16)xr[c] : (_Float16)0.0f;
            }
        }
    }
    __syncthreads();

    const unsigned int* ld = (const unsigned int*)tile;  // dword view (17/col)
    u4* dst = xH + ((size_t)g * V_IN + c0) * 4;
    #pragma unroll
    for (int it = 0; it < 4; ++it) {
        const int c   = (t >> 2) + it * 64;        // 0..255
        const int sub = t & 3;
        if (c0 + c < V_IN) {
            u4 w;
            w.x = ld[c * 17 + sub * 4 + 0];
            w.y = ld[c * 17 + sub * 4 + 1];
            w.z = ld[c * 17 + sub * 4 + 2];
            w.w = ld[c * 17 + sub * 4 + 3];
            dst[(size_t)c * 4 + sub] = w;          // REGULAR store: stay in L3
        }
    }
}

// ---- pass 2: quad-cooperative fp16 gather, both XCD groups per block ----
__global__ __launch_bounds__(TPB) void icopool_gather_h2(
    const h8* __restrict__ xH,
    const int* __restrict__ nidx,
    float*     __restrict__ out)
{
    const int b   = blockIdx.x;
    const int xcd = b & 7;               // HW round-robin XCD assignment
    const int vb  = b >> 3;              // v-block
    const int sub = threadIdx.x & 3;
    const int lv  = threadIdx.x >> 2;    // 0..63
    const int v   = vb * VPB + lv;
    if (v >= V_OUT) return;
    const int g0  = xcd * GPX;

    const int base = v * K;
    const int i0 = nidx[base + 0];
    const int i1 = nidx[base + 1];
    const int i2 = nidx[base + 2];
    const int i3 = nidx[base + 3];
    const int i4 = nidx[base + 4];
    const int i5 = nidx[base + 5];
    const int i6 = nidx[base + 6];

    const h8* s0 = xH + ((size_t)g0 * V_IN) * 4 + sub;
    const h8* s1 = s0 + (size_t)V_IN * 4;

    const h8 a0 = ntload_h8(s0 + (size_t)i0 * 4);
    const h8 a1 = ntload_h8(s0 + (size_t)i1 * 4);
    const h8 a2 = ntload_h8(s0 + (size_t)i2 * 4);
    const h8 a3 = ntload_h8(s0 + (size_t)i3 * 4);
    const h8 a4 = ntload_h8(s0 + (size_t)i4 * 4);
    const h8 a5 = ntload_h8(s0 + (size_t)i5 * 4);
    const h8 a6 = ntload_h8(s0 + (size_t)i6 * 4);
    const h8 b0 = ntload_h8(s1 + (size_t)i0 * 4);
    const h8 b1 = ntload_h8(s1 + (size_t)i1 * 4);
    const h8 b2 = ntload_h8(s1 + (size_t)i2 * 4);
    const h8 b3 = ntload_h8(s1 + (size_t)i3 * 4);
    const h8 b4 = ntload_h8(s1 + (size_t)i4 * 4);
    const h8 b5 = ntload_h8(s1 + (size_t)i5 * 4);
    const h8 b6 = ntload_h8(s1 + (size_t)i6 * 4);

    f8 acc0 = __builtin_convertvector(a0, f8);
    acc0 += __builtin_convertvector(a1, f8);
    acc0 += __builtin_convertvector(a2, f8);
    acc0 += __builtin_convertvector(a3, f8);
    acc0 += __builtin_convertvector(a4, f8);
    acc0 += __builtin_convertvector(a5, f8);
    acc0 += __builtin_convertvector(a6, f8);
    acc0 *= (1.0f / 7.0f);
    f8 acc1 = __builtin_convertvector(b0, f8);
    acc1 += __builtin_convertvector(b1, f8);
    acc1 += __builtin_convertvector(b2, f8);
    acc1 += __builtin_convertvector(b3, f8);
    acc1 += __builtin_convertvector(b4, f8);
    acc1 += __builtin_convertvector(b5, f8);
    acc1 += __builtin_convertvector(b6, f8);
    acc1 *= (1.0f / 7.0f);

    float* o0 = out + (size_t)(g0 * RG + sub * 8) * V_OUT + v;
    float* o1 = o0 + (size_t)RG * V_OUT;
    #pragma unroll
    for (int rr = 0; rr < 8; ++rr) {
        __builtin_nontemporal_store(acc0[rr], o0 + (size_t)rr * V_OUT);
        __builtin_nontemporal_store(acc1[rr], o1 + (size_t)rr * V_OUT);
    }
}

// ---------------- fallback (v1): direct gather, no workspace ----------------
constexpr int RPB  = 2;
constexpr int RGS  = ROWS / RPB;
constexpr int RG_PER_XCD = RGS / 8;
constexpr int VB1  = (V_OUT + TPB - 1) / TPB;
constexpr int BLOCKS_V1  = RGS * VB1;

__global__ __launch_bounds__(TPB) void icopool_gather(
    const float* __restrict__ x,
    const int*   __restrict__ nidx,
    float*       __restrict__ out)
{
    const int b        = blockIdx.x;
    const int xcd      = b & 7;
    const int j        = b >> 3;
    const int rg_local = j / VB1;
    const int vb       = j % VB1;
    const int rg       = xcd * RG_PER_XCD + rg_local;
    const int r0       = rg * RPB;

    const int v = vb * TPB + threadIdx.x;
    if (v >= V_OUT) return;

    const int base = v * K;
    const int i0 = nidx[base + 0];
    const int i1 = nidx[base + 1];
    const int i2 = nidx[base + 2];
    const int i3 = nidx[base + 3];
    const int i4 = nidx[base + 4];
    const int i5 = nidx[base + 5];
    const int i6 = nidx[base + 6];

    #pragma unroll
    for (int r = 0; r < RPB; ++r) {
        const float* xr = x + (size_t)(r0 + r) * V_IN;
        float sum = xr[i0] + xr[i1] + xr[i2] + xr[i3] + xr[i4] + xr[i5] + xr[i6];
        __builtin_nontemporal_store(sum * (1.0f / 7.0f),
                                    out + (size_t)(r0 + r) * V_OUT + v);
    }
}

extern "C" void kernel_launch(void* const* d_in, const int* in_sizes, int n_in,
                              void* d_out, int out_size, void* d_ws, size_t ws_size,
                              hipStream_t stream) {
    const float* x    = (const float*)d_in[0];
    const int*   nidx = (const int*)d_in[1];
    float*       out  = (float*)d_out;

    if (ws_size >= XH_BYTES && d_ws != nullptr) {
        u4* xH = (u4*)d_ws;
        icopool_pack_h<<<dim3(IBX, NG), dim3(TPB), 0, stream>>>(x, xH);
        icopool_gather_h2<<<dim3(BLOCKS2), dim3(TPB), 0, stream>>>((const h8*)xH, nidx, out);
    } else {
        icopool_gather<<<dim3(BLOCKS_V1), dim3(TPB), 0, stream>>>(x, nidx, out);
    }
}

// Round 10
// 583.688 us; speedup vs baseline: 1.0673x; 1.0673x over previous
//
#include <hip/hip_runtime.h>

// IcoPool: out[b,f,v] = mean_{k<7} x[b,f,idx[v,k]]
// x: (8, 64, 163842) f32, idx: (40962, 7) int32, out: (8, 64, 40962) f32
//
// v2-v8: interleaved fp16 slab (64B entry = 32 rows of one vertex),
//   quad-cooperative full-line gathers (fills = bytes/64, minimal), L3-aware
//   store/load hints. v9 (nt gather loads) REGRESSED +60us -> reverted.
// v10: gather fill rate 0.047/cyc/CU implies ~HBM latency (1380cy at C=65
//   measured L2-resident in r3) -> slab is NOT L3-resident: pass 1's 335MB of
//   x reads evict the 168MB slab from the memory-side Infinity Cache before
//   gather runs. Fix: a ~28us slab re-touch kernel between pack and gather
//   re-promotes all slab lines into L3 (read-allocate), so gather fills at
//   true L3 latency instead of HBM.

typedef float    f4 __attribute__((ext_vector_type(4)));
typedef float    f8 __attribute__((ext_vector_type(8)));
typedef _Float16 h8 __attribute__((ext_vector_type(8)));
typedef unsigned int u4 __attribute__((ext_vector_type(4)));

constexpr int B = 8, F = 64, V_IN = 163842, V_OUT = 40962, K = 7;
constexpr int ROWS = B * F;                        // 512
constexpr int RG   = 32;                           // rows per entry (64 B fp16)
constexpr int NG   = ROWS / RG;                    // 16 groups
constexpr int TPB  = 256;
constexpr int GPX  = NG / 8;                       // 2 groups per XCD
// pass 1
constexpr int CPB  = 256;                          // columns per block
constexpr int IBX  = (V_IN + CPB - 1) / CPB;       // 641
constexpr int LSH  = 34;                           // LDS halves per column (32+pad)
// pass 2
constexpr int VPB  = 64;                           // v per block (4 lanes each)
constexpr int VB   = (V_OUT + VPB - 1) / VPB;      // 641
constexpr int BLOCKS2 = 8 * VB;                    // 5128 (both groups per block)
constexpr size_t XH_BYTES = (size_t)NG * V_IN * 64; // 167.8 MB
constexpr int XH_U4 = NG * V_IN * 4;               // 10,485,888 u4 elements

// ---- pass 1: transpose-pack 32 f32 rows -> 64B fp16 entries, via LDS ----
__global__ __launch_bounds__(TPB) void icopool_pack_h(
    const float* __restrict__ x, u4* __restrict__ xH)
{
    __shared__ _Float16 tile[CPB * LSH];           // 17408 B
    const int g  = blockIdx.y;
    const int c0 = blockIdx.x * CPB;
    const int t  = threadIdx.x;
    const int r  = t >> 3;                         // 0..31
    const int ci = t & 7;

    const float* xr = x + (size_t)(g * RG + r) * V_IN;
    if (c0 + CPB <= V_IN) {
        #pragma unroll
        for (int it = 0; it < 4; ++it) {
            const int c8 = ci * 8 + it * 64;
            const f4 v0 = __builtin_nontemporal_load((const f4*)(xr + c0 + c8));
            const f4 v1 = __builtin_nontemporal_load((const f4*)(xr + c0 + c8 + 4));
            tile[(c8 + 0) * LSH + r] = (_Float16)v0.x;
            tile[(c8 + 1) * LSH + r] = (_Float16)v0.y;
            tile[(c8 + 2) * LSH + r] = (_Float16)v0.z;
            tile[(c8 + 3) * LSH + r] = (_Float16)v0.w;
            tile[(c8 + 4) * LSH + r] = (_Float16)v1.x;
            tile[(c8 + 5) * LSH + r] = (_Float16)v1.y;
            tile[(c8 + 6) * LSH + r] = (_Float16)v1.z;
            tile[(c8 + 7) * LSH + r] = (_Float16)v1.w;
        }
    } else {
        for (int it = 0; it < 4; ++it) {
            const int c8 = ci * 8 + it * 64;
            for (int jj = 0; jj < 8; ++jj) {
                const int c = c0 + c8 + jj;
                tile[(c8 + jj) * LSH + r] =
                    (c < V_IN) ? (_Float16)xr[c] : (_Float16)0.0f;
            }
        }
    }
    __syncthreads();

    const unsigned int* ld = (const unsigned int*)tile;  // dword view (17/col)
    u4* dst = xH + ((size_t)g * V_IN + c0) * 4;
    #pragma unroll
    for (int it = 0; it < 4; ++it) {
        const int c   = (t >> 2) + it * 64;        // 0..255
        const int sub = t & 3;
        if (c0 + c < V_IN) {
            u4 w;
            w.x = ld[c * 17 + sub * 4 + 0];
            w.y = ld[c * 17 + sub * 4 + 1];
            w.z = ld[c * 17 + sub * 4 + 2];
            w.w = ld[c * 17 + sub * 4 + 3];
            dst[(size_t)c * 4 + sub] = w;          // REGULAR store: allocate L3
        }
    }
}

// ---- pass 1.5: re-promote the slab into the Infinity Cache ----
// Pass 1's 335 MB of x reads evicted most of the 168 MB slab from L3.
// A sequential streaming read re-allocates every slab line in L3 (~28 us),
// so pass 2 fills at L3 latency instead of HBM latency.
__global__ __launch_bounds__(TPB) void icopool_touch(const u4* __restrict__ xH)
{
    const size_t stride = (size_t)gridDim.x * TPB;
    for (size_t i = (size_t)blockIdx.x * TPB + threadIdx.x; i < (size_t)XH_U4;
         i += stride) {
        u4 w = xH[i];
        asm volatile("" :: "v"(w.x), "v"(w.y), "v"(w.z), "v"(w.w));
    }
}

// ---- pass 2: quad-cooperative fp16 gather, both XCD groups per block ----
__global__ __launch_bounds__(TPB) void icopool_gather_h2(
    const h8* __restrict__ xH,
    const int* __restrict__ nidx,
    float*     __restrict__ out)
{
    const int b   = blockIdx.x;
    const int xcd = b & 7;               // HW round-robin XCD assignment
    const int vb  = b >> 3;              // v-block
    const int sub = threadIdx.x & 3;
    const int lv  = threadIdx.x >> 2;    // 0..63
    const int v   = vb * VPB + lv;
    if (v >= V_OUT) return;
    const int g0  = xcd * GPX;

    const int base = v * K;
    const int i0 = nidx[base + 0];
    const int i1 = nidx[base + 1];
    const int i2 = nidx[base + 2];
    const int i3 = nidx[base + 3];
    const int i4 = nidx[base + 4];
    const int i5 = nidx[base + 5];
    const int i6 = nidx[base + 6];

    const h8* s0 = xH + ((size_t)g0 * V_IN) * 4 + sub;
    const h8* s1 = s0 + (size_t)V_IN * 4;

    const h8 a0 = s0[(size_t)i0 * 4];
    const h8 a1 = s0[(size_t)i1 * 4];
    const h8 a2 = s0[(size_t)i2 * 4];
    const h8 a3 = s0[(size_t)i3 * 4];
    const h8 a4 = s0[(size_t)i4 * 4];
    const h8 a5 = s0[(size_t)i5 * 4];
    const h8 a6 = s0[(size_t)i6 * 4];
    const h8 b0 = s1[(size_t)i0 * 4];
    const h8 b1 = s1[(size_t)i1 * 4];
    const h8 b2 = s1[(size_t)i2 * 4];
    const h8 b3 = s1[(size_t)i3 * 4];
    const h8 b4 = s1[(size_t)i4 * 4];
    const h8 b5 = s1[(size_t)i5 * 4];
    const h8 b6 = s1[(size_t)i6 * 4];

    f8 acc0 = __builtin_convertvector(a0, f8);
    acc0 += __builtin_convertvector(a1, f8);
    acc0 += __builtin_convertvector(a2, f8);
    acc0 += __builtin_convertvector(a3, f8);
    acc0 += __builtin_convertvector(a4, f8);
    acc0 += __builtin_convertvector(a5, f8);
    acc0 += __builtin_convertvector(a6, f8);
    acc0 *= (1.0f / 7.0f);
    f8 acc1 = __builtin_convertvector(b0, f8);
    acc1 += __builtin_convertvector(b1, f8);
    acc1 += __builtin_convertvector(b2, f8);
    acc1 += __builtin_convertvector(b3, f8);
    acc1 += __builtin_convertvector(b4, f8);
    acc1 += __builtin_convertvector(b5, f8);
    acc1 += __builtin_convertvector(b6, f8);
    acc1 *= (1.0f / 7.0f);

    float* o0 = out + (size_t)(g0 * RG + sub * 8) * V_OUT + v;
    float* o1 = o0 + (size_t)RG * V_OUT;
    #pragma unroll
    for (int rr = 0; rr < 8; ++rr) {
        __builtin_nontemporal_store(acc0[rr], o0 + (size_t)rr * V_OUT);
        __builtin_nontemporal_store(acc1[rr], o1 + (size_t)rr * V_OUT);
    }
}

// ---------------- fallback (v1): direct gather, no workspace ----------------
constexpr int RPB  = 2;
constexpr int RGS  = ROWS / RPB;
constexpr int RG_PER_XCD = RGS / 8;
constexpr int VB1  = (V_OUT + TPB - 1) / TPB;
constexpr int BLOCKS_V1  = RGS * VB1;

__global__ __launch_bounds__(TPB) void icopool_gather(
    const float* __restrict__ x,
    const int*   __restrict__ nidx,
    float*       __restrict__ out)
{
    const int b        = blockIdx.x;
    const int xcd      = b & 7;
    const int j        = b >> 3;
    const int rg_local = j / VB1;
    const int vb       = j % VB1;
    const int rg       = xcd * RG_PER_XCD + rg_local;
    const int r0       = rg * RPB;

    const int v = vb * TPB + threadIdx.x;
    if (v >= V_OUT) return;

    const int base = v * K;
    const int i0 = nidx[base + 0];
    const int i1 = nidx[base + 1];
    const int i2 = nidx[base + 2];
    const int i3 = nidx[base + 3];
    const int i4 = nidx[base + 4];
    const int i5 = nidx[base + 5];
    const int i6 = nidx[base + 6];

    #pragma unroll
    for (int r = 0; r < RPB; ++r) {
        const float* xr = x + (size_t)(r0 + r) * V_IN;
        float sum = xr[i0] + xr[i1] + xr[i2] + xr[i3] + xr[i4] + xr[i5] + xr[i6];
        __builtin_nontemporal_store(sum * (1.0f / 7.0f),
                                    out + (size_t)(r0 + r) * V_OUT + v);
    }
}

extern "C" void kernel_launch(void* const* d_in, const int* in_sizes, int n_in,
                              void* d_out, int out_size, void* d_ws, size_t ws_size,
                              hipStream_t stream) {
    const float* x    = (const float*)d_in[0];
    const int*   nidx = (const int*)d_in[1];
    float*       out  = (float*)d_out;

    if (ws_size >= XH_BYTES && d_ws != nullptr) {
        u4* xH = (u4*)d_ws;
        icopool_pack_h<<<dim3(IBX, NG), dim3(TPB), 0, stream>>>(x, xH);
        icopool_touch<<<dim3(2048), dim3(TPB), 0, stream>>>(xH);
        icopool_gather_h2<<<dim3(BLOCKS2), dim3(TPB), 0, stream>>>((const h8*)xH, nidx, out);
    } else {
        icopool_gather<<<dim3(BLOCKS_V1), dim3(TPB), 0, stream>>>(x, nidx, out);
    }
}

// Round 11
// 582.867 us; speedup vs baseline: 1.0688x; 1.0014x over previous
//
#include <hip/hip_runtime.h>

// IcoPool: out[b,f,v] = mean_{k<7} x[b,f,idx[v,k]]
// x: (8, 64, 163842) f32, idx: (40962, 7) int32, out: (8, 64, 40962) f32
//
// v2-v8: interleaved fp16 slab, quad-cooperative full-line gathers, L2/L3
//   window blocking, fp16 (fills halved). v9 (nt gather loads) REGRESSED.
//   v10 (L3 re-touch) NULL -> L3-vs-HBM residency doesn't change random-fill
//   rate (per-CU concurrency cap ~65 lines; rate = cap/latency).
// v11: only remaining gather lever = convert fabric fills to L2 hits by
//   shrinking the per-XCD window. RG 32 -> 16 (32B entries, NG=32, GPX=4),
//   gather merges TWO groups per block: per-thread profile IDENTICAL to v8
//   (7 idx + 14x16B loads + 16 stores) but window 21MB -> 10.5MB. Touch
//   kernel dropped. Clean A/B on window size.

typedef float    f4 __attribute__((ext_vector_type(4)));
typedef float    f8 __attribute__((ext_vector_type(8)));
typedef _Float16 h8 __attribute__((ext_vector_type(8)));
typedef unsigned int u4 __attribute__((ext_vector_type(4)));

constexpr int B = 8, F = 64, V_IN = 163842, V_OUT = 40962, K = 7;
constexpr int ROWS = B * F;                        // 512
constexpr int RG   = 16;                           // rows per entry (32 B fp16)
constexpr int NG   = ROWS / RG;                    // 32 groups
constexpr int TPB  = 256;
constexpr int GPX  = NG / 8;                       // 4 groups per XCD
// pass 1
constexpr int CPB  = 256;                          // columns per block
constexpr int IBX  = (V_IN + CPB - 1) / CPB;       // 641
constexpr int LSH  = 18;                           // LDS halves per column (16+2 pad, dword-aligned)
// pass 2
constexpr int VPB  = 128;                          // v per block (2 lanes each)
constexpr int VB   = (V_OUT + VPB - 1) / VPB;      // 321
constexpr int NGL  = 2;                            // merged-group sets per XCD
constexpr int BLOCKS2 = 8 * NGL * VB;              // 5136
constexpr size_t XH_BYTES = (size_t)NG * V_IN * 32; // 167.8 MB

// ---- pass 1: transpose-pack 16 f32 rows -> 32B fp16 entries, via LDS ----
__global__ __launch_bounds__(TPB) void icopool_pack_h16(
    const float* __restrict__ x, u4* __restrict__ xH)
{
    __shared__ _Float16 tile[CPB * LSH];           // 9216 B
    const int g  = blockIdx.y;
    const int c0 = blockIdx.x * CPB;
    const int t  = threadIdx.x;

    // Phase A: coalesced f4 row reads (nt: x is read exactly once), cvt fp16,
    // store column-major into LDS.
    if (c0 + CPB <= V_IN) {
        #pragma unroll
        for (int it = 0; it < 4; ++it) {
            const int r  = it * 4 + (t >> 6);      // 0..15
            const int c4 = (t & 63) * 4;
            const float* xr = x + (size_t)(g * RG + r) * V_IN + c0;
            const f4 vv = __builtin_nontemporal_load((const f4*)(xr + c4));
            tile[(c4 + 0) * LSH + r] = (_Float16)vv.x;
            tile[(c4 + 1) * LSH + r] = (_Float16)vv.y;
            tile[(c4 + 2) * LSH + r] = (_Float16)vv.z;
            tile[(c4 + 3) * LSH + r] = (_Float16)vv.w;
        }
    } else {
        for (int it = 0; it < 4; ++it) {
            const int r  = it * 4 + (t >> 6);
            const int c4 = (t & 63) * 4;
            const float* xr = x + (size_t)(g * RG + r) * V_IN;
            for (int jj = 0; jj < 4; ++jj) {
                const int c = c0 + c4 + jj;
                tile[(c4 + jj) * LSH + r] =
                    (c < V_IN) ? (_Float16)xr[c] : (_Float16)0.0f;
            }
        }
    }
    __syncthreads();

    // Phase B: entry c = 32B (16 rows); lane (c=t>>1, sub=t&1) emits one u4.
    // Consecutive lanes -> consecutive u4: fully coalesced 16B/lane stores.
    const unsigned int* ld = (const unsigned int*)tile;  // 9 dwords per col
    u4* dst = xH + ((size_t)g * V_IN) * 2;
    #pragma unroll
    for (int it = 0; it < 2; ++it) {
        const int c   = (t >> 1) + it * 128;       // 0..255
        const int sub = t & 1;
        if (c0 + c < V_IN) {
            const int p = c * 9 + sub * 4;
            u4 w;
            w.x = ld[p + 0];
            w.y = ld[p + 1];
            w.z = ld[p + 2];
            w.w = ld[p + 3];
            dst[((size_t)(c0 + c)) * 2 + sub] = w; // REGULAR store: allocate L2/L3
        }
    }
}

// ---- pass 2: pair-cooperative fp16 gather, two groups per block ----
// sub is wave-uniform (wave parity) so every store is 256B contiguous.
// Per thread: 7 idx + 14x16B gather loads + 16 nt stores (same as v8);
// per-XCD instantaneous window = 2 group slabs = 10.5 MB (was 21 MB).
__global__ __launch_bounds__(TPB) void icopool_gather_h16(
    const h8* __restrict__ xH,
    const int* __restrict__ nidx,
    float*     __restrict__ out)
{
    const int b   = blockIdx.x;
    const int xcd = b & 7;               // HW round-robin XCD assignment
    const int j   = b >> 3;
    const int gl  = j / VB;              // merged-group set (slow)
    const int vb  = j % VB;              // v-block (fast -> window stays hot)
    const int t   = threadIdx.x;
    const int w   = t >> 6;              // wave id 0..3
    const int sub = w & 1;               // wave-uniform half-entry selector
    const int lv  = (t & 63) | ((w >> 1) << 6);    // 0..127
    const int v   = vb * VPB + lv;
    if (v >= V_OUT) return;

    const int g0  = xcd * GPX + gl * 2;  // this block's two groups

    const int base = v * K;
    const int i0 = nidx[base + 0];
    const int i1 = nidx[base + 1];
    const int i2 = nidx[base + 2];
    const int i3 = nidx[base + 3];
    const int i4 = nidx[base + 4];
    const int i5 = nidx[base + 5];
    const int i6 = nidx[base + 6];

    const h8* s0 = xH + ((size_t)g0 * V_IN) * 2 + sub;
    const h8* s1 = s0 + (size_t)V_IN * 2;

    const h8 a0 = s0[(size_t)i0 * 2];
    const h8 a1 = s0[(size_t)i1 * 2];
    const h8 a2 = s0[(size_t)i2 * 2];
    const h8 a3 = s0[(size_t)i3 * 2];
    const h8 a4 = s0[(size_t)i4 * 2];
    const h8 a5 = s0[(size_t)i5 * 2];
    const h8 a6 = s0[(size_t)i6 * 2];
    const h8 b0 = s1[(size_t)i0 * 2];
    const h8 b1 = s1[(size_t)i1 * 2];
    const h8 b2 = s1[(size_t)i2 * 2];
    const h8 b3 = s1[(size_t)i3 * 2];
    const h8 b4 = s1[(size_t)i4 * 2];
    const h8 b5 = s1[(size_t)i5 * 2];
    const h8 b6 = s1[(size_t)i6 * 2];

    f8 acc0 = __builtin_convertvector(a0, f8);
    acc0 += __builtin_convertvector(a1, f8);
    acc0 += __builtin_convertvector(a2, f8);
    acc0 += __builtin_convertvector(a3, f8);
    acc0 += __builtin_convertvector(a4, f8);
    acc0 += __builtin_convertvector(a5, f8);
    acc0 += __builtin_convertvector(a6, f8);
    acc0 *= (1.0f / 7.0f);
    f8 acc1 = __builtin_convertvector(b0, f8);
    acc1 += __builtin_convertvector(b1, f8);
    acc1 += __builtin_convertvector(b2, f8);
    acc1 += __builtin_convertvector(b3, f8);
    acc1 += __builtin_convertvector(b4, f8);
    acc1 += __builtin_convertvector(b5, f8);
    acc1 += __builtin_convertvector(b6, f8);
    acc1 *= (1.0f / 7.0f);

    float* o0 = out + (size_t)(g0 * RG + sub * 8) * V_OUT + v;
    float* o1 = o0 + (size_t)RG * V_OUT;   // next group = +16 rows
    #pragma unroll
    for (int rr = 0; rr < 8; ++rr) {
        __builtin_nontemporal_store(acc0[rr], o0 + (size_t)rr * V_OUT);
        __builtin_nontemporal_store(acc1[rr], o1 + (size_t)rr * V_OUT);
    }
}

// ---------------- fallback (v1): direct gather, no workspace ----------------
constexpr int RPB  = 2;
constexpr int RGS  = ROWS / RPB;
constexpr int RG_PER_XCD = RGS / 8;
constexpr int VB1  = (V_OUT + TPB - 1) / TPB;
constexpr int BLOCKS_V1  = RGS * VB1;

__global__ __launch_bounds__(TPB) void icopool_gather(
    const float* __restrict__ x,
    const int*   __restrict__ nidx,
    float*       __restrict__ out)
{
    const int b        = blockIdx.x;
    const int xcd      = b & 7;
    const int j        = b >> 3;
    const int rg_local = j / VB1;
    const int vb       = j % VB1;
    const int rg       = xcd * RG_PER_XCD + rg_local;
    const int r0       = rg * RPB;

    const int v = vb * TPB + threadIdx.x;
    if (v >= V_OUT) return;

    const int base = v * K;
    const int i0 = nidx[base + 0];
    const int i1 = nidx[base + 1];
    const int i2 = nidx[base + 2];
    const int i3 = nidx[base + 3];
    const int i4 = nidx[base + 4];
    const int i5 = nidx[base + 5];
    const int i6 = nidx[base + 6];

    #pragma unroll
    for (int r = 0; r < RPB; ++r) {
        const float* xr = x + (size_t)(r0 + r) * V_IN;
        float sum = xr[i0] + xr[i1] + xr[i2] + xr[i3] + xr[i4] + xr[i5] + xr[i6];
        __builtin_nontemporal_store(sum * (1.0f / 7.0f),
                                    out + (size_t)(r0 + r) * V_OUT + v);
    }
}

extern "C" void kernel_launch(void* const* d_in, const int* in_sizes, int n_in,
                              void* d_out, int out_size, void* d_ws, size_t ws_size,
                              hipStream_t stream) {
    const float* x    = (const float*)d_in[0];
    const int*   nidx = (const int*)d_in[1];
    float*       out  = (float*)d_out;

    if (ws_size >= XH_BYTES && d_ws != nullptr) {
        u4* xH = (u4*)d_ws;
        icopool_pack_h16<<<dim3(IBX, NG), dim3(TPB), 0, stream>>>(x, xH);
        icopool_gather_h16<<<dim3(BLOCKS2), dim3(TPB), 0, stream>>>((const h8*)xH, nidx, out);
    } else {
        icopool_gather<<<dim3(BLOCKS_V1), dim3(TPB), 0, stream>>>(x, nidx, out);
    }
}

// Round 12
// 540.667 us; speedup vs baseline: 1.1522x; 1.0781x over previous
//
#include <hip/hip_runtime.h>

// IcoPool: out[b,f,v] = mean_{k<7} x[b,f,idx[v,k]]
// x: (8, 64, 163842) f32, idx: (40962, 7) int32, out: (8, 64, 40962) f32
//
// Model (r0-r11): gather requests = gathered_bytes/16B = 18.3M invariant.
//   Service: L2-hit ~0.27 random-16B/cyc/CU (r3), fabric-fill ~0.19 (v8),
//   partial-line entries pay 2x bytes (v11 +20us). v8 best: 64B entries,
//   fabric regime, gather ~157us.
// v12: reach the L2-resident regime. RG=8 -> 16B entry (one full lane req),
//   slab/group = 2.62MB. Group-outer phases (8/XCD, vb fastest). Residency
//   capped to 4 blocks/CU via 40KB LDS limiter -> cohort 128 < phase 161
//   blocks -> live window ~1.3 slabs ~3.4MB < 4MB L2. idx staged coalesced
//   via LDS (TA-relevant in hit regime). Pack: no-LDS 2-col/thread (reads
//   f2 coalesced, writes full 16B entries).

typedef float    f2 __attribute__((ext_vector_type(2)));
typedef float    f8 __attribute__((ext_vector_type(8)));
typedef _Float16 h8 __attribute__((ext_vector_type(8)));
typedef unsigned int u4 __attribute__((ext_vector_type(4)));

constexpr int B = 8, F = 64, V_IN = 163842, V_OUT = 40962, K = 7;
constexpr int ROWS = B * F;                        // 512
constexpr int RG   = 8;                            // rows per entry (16 B fp16)
constexpr int NG   = ROWS / RG;                    // 64 groups
constexpr int TPB  = 256;
constexpr int GPX  = NG / 8;                       // 8 groups per XCD
// pass 1
constexpr int CPB1 = 2 * TPB;                      // 512 cols per block
constexpr int IBX  = (V_IN + CPB1 - 1) / CPB1;     // 321
// pass 2
constexpr int VB   = (V_OUT + TPB - 1) / TPB;      // 161 v-blocks per group
constexpr int BLOCKS2 = 8 * GPX * VB;              // 10304
constexpr size_t XH_BYTES = (size_t)NG * V_IN * 16; // 167.8 MB

// ---- pass 1: pack 8 f32 rows -> 16B fp16 entries (no LDS) ----
// lane t: cols c0, c0+1. Reads: 8 rows x f2, coalesced 512B/wave, nt (x is
// read once). Writes: 2 full entries (16B each), regular (v8 lesson: let the
// slab allocate in cache).
__global__ __launch_bounds__(TPB) void icopool_pack_h8(
    const float* __restrict__ x, u4* __restrict__ xH)
{
    const int g  = blockIdx.y;
    const int c0 = blockIdx.x * CPB1 + threadIdx.x * 2;
    if (c0 >= V_IN) return;
    const float* xp = x + (size_t)g * RG * V_IN + c0;
    h8 e0, e1;
    #pragma unroll
    for (int r = 0; r < 8; ++r) {
        const f2 v = __builtin_nontemporal_load((const f2*)(xp + (size_t)r * V_IN));
        e0[r] = (_Float16)v.x;
        e1[r] = (_Float16)v.y;
    }
    union { h8 h; u4 u; } cv0, cv1;
    cv0.h = e0; cv1.h = e1;
    u4* dst = xH + ((size_t)g * V_IN + c0);
    dst[0] = cv0.u;
    dst[1] = cv1.u;
}

// ---- pass 2: L2-resident gather. One 16B entry load per (v,k). ----
// Occupancy deliberately capped at 4 blocks/CU by the LDS footprint (~40KB):
// resident cohort 128 blocks/XCD < 161 blocks/phase -> only ~1.3 group slabs
// (3.4MB) live per XCD L2 at any time. idx staged coalesced through LDS.
__global__ __launch_bounds__(TPB) void icopool_gather_h8(
    const u4* __restrict__ xH,
    const int* __restrict__ nidx,
    float*     __restrict__ out)
{
    __shared__ int sidx[TPB * K];                  // 7168 B
    __shared__ int limiter[8192];                  // 32768 B -> 4 blocks/CU cap
    const int b   = blockIdx.x;
    const int xcd = b & 7;               // HW round-robin XCD assignment
    const int j   = b >> 3;
    const int gl  = j / VB;              // group within XCD (slow)
    const int vb  = j % VB;              // v-block (fast -> slab stays hot)
    const int t   = threadIdx.x;

    // coalesced idx stage: flat copy of this v-block's 1792 ints
    const int fbase = vb * (TPB * K);
    #pragma unroll
    for (int k = 0; k < K; ++k) {
        const int off = k * TPB + t;
        sidx[off] = (fbase + off < V_OUT * K) ? nidx[fbase + off] : 0;
    }
    if (t == 0) limiter[0] = 1;          // keep limiter allocation live
    __syncthreads();

    const int v = vb * TPB + t;
    if (v >= V_OUT) return;
    const int g = xcd * GPX + gl;

    const int* my = sidx + t * K;
    const u4* s = xH + (size_t)g * V_IN;
    const u4 q0 = s[(size_t)my[0]];
    const u4 q1 = s[(size_t)my[1]];
    const u4 q2 = s[(size_t)my[2]];
    const u4 q3 = s[(size_t)my[3]];
    const u4 q4 = s[(size_t)my[4]];
    const u4 q5 = s[(size_t)my[5]];
    const u4 q6 = s[(size_t)my[6]];

    union { u4 u; h8 h; } c0, c1, c2, c3, c4, c5, c6;
    c0.u = q0; c1.u = q1; c2.u = q2; c3.u = q3; c4.u = q4; c5.u = q5; c6.u = q6;
    f8 acc = __builtin_convertvector(c0.h, f8);
    acc += __builtin_convertvector(c1.h, f8);
    acc += __builtin_convertvector(c2.h, f8);
    acc += __builtin_convertvector(c3.h, f8);
    acc += __builtin_convertvector(c4.h, f8);
    acc += __builtin_convertvector(c5.h, f8);
    acc += __builtin_convertvector(c6.h, f8);
    acc *= (1.0f / 7.0f);

    float* o = out + (size_t)(g * RG) * V_OUT + v;
    #pragma unroll
    for (int rr = 0; rr < 8; ++rr)
        __builtin_nontemporal_store(acc[rr], o + (size_t)rr * V_OUT);
}

// ---------------- fallback (v1): direct gather, no workspace ----------------
constexpr int RPB  = 2;
constexpr int RGS  = ROWS / RPB;
constexpr int RG_PER_XCD = RGS / 8;
constexpr int VB1  = (V_OUT + TPB - 1) / TPB;
constexpr int BLOCKS_V1  = RGS * VB1;

__global__ __launch_bounds__(TPB) void icopool_gather(
    const float* __restrict__ x,
    const int*   __restrict__ nidx,
    float*       __restrict__ out)
{
    const int b        = blockIdx.x;
    const int xcd      = b & 7;
    const int j        = b >> 3;
    const int rg_local = j / VB1;
    const int vb       = j % VB1;
    const int rg       = xcd * RG_PER_XCD + rg_local;
    const int r0       = rg * RPB;

    const int v = vb * TPB + threadIdx.x;
    if (v >= V_OUT) return;

    const int base = v * K;
    const int i0 = nidx[base + 0];
    const int i1 = nidx[base + 1];
    const int i2 = nidx[base + 2];
    const int i3 = nidx[base + 3];
    const int i4 = nidx[base + 4];
    const int i5 = nidx[base + 5];
    const int i6 = nidx[base + 6];

    #pragma unroll
    for (int r = 0; r < RPB; ++r) {
        const float* xr = x + (size_t)(r0 + r) * V_IN;
        float sum = xr[i0] + xr[i1] + xr[i2] + xr[i3] + xr[i4] + xr[i5] + xr[i6];
        __builtin_nontemporal_store(sum * (1.0f / 7.0f),
                                    out + (size_t)(r0 + r) * V_OUT + v);
    }
}

extern "C" void kernel_launch(void* const* d_in, const int* in_sizes, int n_in,
                              void* d_out, int out_size, void* d_ws, size_t ws_size,
                              hipStream_t stream) {
    const float* x    = (const float*)d_in[0];
    const int*   nidx = (const int*)d_in[1];
    float*       out  = (float*)d_out;

    if (ws_size >= XH_BYTES && d_ws != nullptr) {
        u4* xH = (u4*)d_ws;
        icopool_pack_h8<<<dim3(IBX, NG), dim3(TPB), 0, stream>>>(x, xH);
        icopool_gather_h8<<<dim3(BLOCKS2), dim3(TPB), 0, stream>>>(xH, nidx, out);
    } else {
        icopool_gather<<<dim3(BLOCKS_V1), dim3(TPB), 0, stream>>>(x, nidx, out);
    }
}